// Round 3
// baseline (267.161 us; speedup 1.0000x reference)
//
#include <hip/hip_runtime.h>
#include <stdint.h>

// SE block, float32: x[32,256,56,56] -> out = x * sigmoid(MLP(mean_hw(x)))
// B=32, CH=256, BOT=32, HW=56*56=3136
#define BATCH 32
#define CH    256
#define BOT   32
#define HW    3136
#define CHUNKS_PER_PLANE 784          // HW / 4 floats per float4

// ---------------- Kernel A: global average pool ----------------
// One wave (64 lanes) per (b,c) plane; block = 4 waves = 4 planes.
// grid = 8192/4 = 2048 blocks. Plane = 784 float4 chunks, base 16B-aligned.
__global__ __launch_bounds__(256) void pool_kernel(
        const float* __restrict__ x, float* __restrict__ s_out) {
    const int wave = threadIdx.x >> 6;
    const int lane = threadIdx.x & 63;
    const int bc = blockIdx.x * 4 + wave;   // < 8192

    const float4* p4 = (const float4*)(x + (size_t)bc * HW);
    float sum = 0.f;
    #pragma unroll
    for (int i = 0; i < 13; ++i) {          // 13*64 = 832 >= 784
        int idx = lane + i * 64;
        if (idx < CHUNKS_PER_PLANE) {
            float4 v = p4[idx];
            sum += (v.x + v.y) + (v.z + v.w);
        }
    }
    #pragma unroll
    for (int off = 32; off > 0; off >>= 1)
        sum += __shfl_down(sum, off, 64);
    if (lane == 0) s_out[bc] = sum * (1.0f / (float)HW);
}

// ---------------- Kernel B: fused MLP + scale ----------------
// One block per (b,c) plane, grid = 8192. Each block redundantly computes
// h[b][:] (32 dots of len 256; 8 lanes per dot, shuffle-reduced) and its own
// gate g[b][c], then scales its 784 float4. Redundant work = 67M FMA total
// (noise). w1 is 32 KB -> L1/L2-hot across all blocks.
__global__ __launch_bounds__(256) void fused_mlp_scale_kernel(
        const float* __restrict__ x, const float* __restrict__ s,
        const float* __restrict__ w1, const float* __restrict__ b1,
        const float* __restrict__ w2, const float* __restrict__ b2,
        float* __restrict__ out) {
    __shared__ float s_lds[CH];   // s[b][:]
    __shared__ float hs[BOT];     // relu hidden
    const int t  = threadIdx.x;
    const int bc = blockIdx.x;    // plane id
    const int b  = bc >> 8;       // batch
    const int c  = bc & 255;      // channel

    // stage s[b][:] into LDS (coalesced, 1 load/thread)
    s_lds[t] = s[b * CH + t];
    __syncthreads();

    // h[o] = relu(b1[o] + dot(s[b], w1[o]))
    // thread t: o = t>>3, part = t&7 covers c in [part*32, part*32+32).
    // Swizzle start by part*4 so the 8 parts hit 8 distinct LDS banks
    // (un-swizzled, all parts hit bank j%32 -> 8-way conflict).
    {
        const int o    = t >> 3;
        const int part = t & 7;
        const float* wrow = w1 + o * CH + part * 32;
        const float* srow = s_lds + part * 32;
        float acc = 0.f;
        #pragma unroll
        for (int j = 0; j < 32; ++j) {
            const int jj = (j + part * 4) & 31;
            acc = fmaf(srow[jj], wrow[jj], acc);
        }
        acc += __shfl_xor(acc, 1, 64);
        acc += __shfl_xor(acc, 2, 64);
        acc += __shfl_xor(acc, 4, 64);
        if (part == 0) hs[o] = fmaxf(acc + b1[o], 0.f);
    }
    __syncthreads();

    // g = sigmoid(b2[c] + dot(h, w2[c])) — redundant per thread; hs[] reads
    // are same-address broadcasts (conflict-free), w2 row is s_load (c uniform).
    float acc = b2[c];
    const float* w2row = w2 + c * BOT;
    #pragma unroll
    for (int o = 0; o < BOT; ++o)
        acc = fmaf(hs[o], w2row[o], acc);
    const float gv = 1.0f / (1.0f + __expf(-acc));

    // scale this plane: 784 float4, coalesced; 3 full rounds of 256 + 16 tail
    const float4* xp = (const float4*)(x + (size_t)bc * HW);
    float4*       op = (float4*)(out + (size_t)bc * HW);
    #pragma unroll
    for (int i = 0; i < 3; ++i) {
        float4 v = xp[t + i * 256];
        v.x *= gv; v.y *= gv; v.z *= gv; v.w *= gv;
        op[t + i * 256] = v;
    }
    if (t < 16) {
        float4 v = xp[768 + t];
        v.x *= gv; v.y *= gv; v.z *= gv; v.w *= gv;
        op[768 + t] = v;
    }
}

extern "C" void kernel_launch(void* const* d_in, const int* in_sizes, int n_in,
                              void* d_out, int out_size, void* d_ws, size_t ws_size,
                              hipStream_t stream) {
    const float* x  = (const float*)d_in[0];
    const float* w1 = (const float*)d_in[1];
    const float* b1 = (const float*)d_in[2];
    const float* w2 = (const float*)d_in[3];
    const float* b2 = (const float*)d_in[4];
    float* out = (float*)d_out;

    float* s = (float*)d_ws;              // 8192 floats = 32 KB

    pool_kernel<<<BATCH * CH / 4, 256, 0, stream>>>(x, s);
    fused_mlp_scale_kernel<<<BATCH * CH, 256, 0, stream>>>(x, s, w1, b1, w2, b2, out);
}

// Round 4
// 202.563 us; speedup vs baseline: 1.3189x; 1.3189x over previous
//
#include <hip/hip_runtime.h>
#include <stdint.h>

// SE block, float32: x[32,256,56,56] -> out = x * sigmoid(MLP(mean_hw(x)))
// B=32, CH=256, BOT=32, HW=56*56=3136
#define BATCH 32
#define CH    256
#define BOT   32
#define HW    3136
#define CHUNKS_PER_PLANE 784                            // HW/4 float4 per plane
#define TOTAL_CHUNKS (BATCH * CH * CHUNKS_PER_PLANE)    // 6,422,528
#define SCALE_BLOCKS (TOTAL_CHUNKS / 1024)              // 6272, 4 chunks/thread

// ---------------- Kernel A: global average pool ----------------
// One wave per (b,c) plane; block = 4 waves = 4 planes. grid = 2048.
__global__ __launch_bounds__(256) void pool_kernel(
        const float* __restrict__ x, float* __restrict__ s_out) {
    const int wave = threadIdx.x >> 6;
    const int lane = threadIdx.x & 63;
    const int bc = blockIdx.x * 4 + wave;   // < 8192

    const float4* p4 = (const float4*)(x + (size_t)bc * HW);
    float sum = 0.f;
    #pragma unroll
    for (int i = 0; i < 13; ++i) {          // 13*64 = 832 >= 784
        int idx = lane + i * 64;
        if (idx < CHUNKS_PER_PLANE) {
            float4 v = p4[idx];
            sum += (v.x + v.y) + (v.z + v.w);
        }
    }
    #pragma unroll
    for (int off = 32; off > 0; off >>= 1)
        sum += __shfl_down(sum, off, 64);
    if (lane == 0) s_out[bc] = sum * (1.0f / (float)HW);
}

// ---------------- Kernel B: MLP, one block per batch row ----------------
// grid = 32, block = 256. Phase 1: h[o] via 8 lanes/output (float4 w1 loads,
// shuffle reduce). Phase 2: thread t = channel c, float4 w2 loads.
// Total global traffic: 32 blocks x (1KB s + 32KB w1 + 32KB w2) ~ 2MB (L2).
__global__ __launch_bounds__(256) void mlp_kernel(
        const float* __restrict__ s,
        const float* __restrict__ w1, const float* __restrict__ b1,
        const float* __restrict__ w2, const float* __restrict__ b2,
        float* __restrict__ g) {
    __shared__ float s_lds[CH];
    __shared__ float hs[BOT];
    const int b = blockIdx.x;
    const int t = threadIdx.x;

    s_lds[t] = s[b * CH + t];
    __syncthreads();

    // h[o] = relu(b1[o] + dot(s[b,:], w1[o,:])); o = t>>3, part = t&7
    {
        const int o = t >> 3;
        const int part = t & 7;
        const float4* w4 = (const float4*)(w1 + o * CH + part * 32);
        const float4* s4 = (const float4*)(s_lds + part * 32);
        float acc = 0.f;
        #pragma unroll
        for (int j = 0; j < 8; ++j) {
            float4 wv = w4[j];
            float4 sv = s4[j];
            acc = fmaf(sv.x, wv.x, acc);
            acc = fmaf(sv.y, wv.y, acc);
            acc = fmaf(sv.z, wv.z, acc);
            acc = fmaf(sv.w, wv.w, acc);
        }
        acc += __shfl_xor(acc, 1, 64);
        acc += __shfl_xor(acc, 2, 64);
        acc += __shfl_xor(acc, 4, 64);
        if (part == 0) hs[o] = fmaxf(acc + b1[o], 0.f);
    }
    __syncthreads();

    // g[b,c] = sigmoid(b2[c] + dot(h, w2[c,:])); c = t
    {
        const float4* w4 = (const float4*)(w2 + t * BOT);
        float acc = b2[t];
        #pragma unroll
        for (int j = 0; j < 8; ++j) {
            float4 wv = w4[j];
            acc = fmaf(hs[j * 4 + 0], wv.x, acc);
            acc = fmaf(hs[j * 4 + 1], wv.y, acc);
            acc = fmaf(hs[j * 4 + 2], wv.z, acc);
            acc = fmaf(hs[j * 4 + 3], wv.w, acc);
        }
        g[b * CH + t] = 1.0f / (1.0f + __expf(-acc));
    }
}

// ---------------- Kernel C: scale ----------------
// 4 float4 per thread, grid = 6272 blocks. Prologue per chunk: one
// magic-div + one scalar (L2-broadcast) g load.
__global__ __launch_bounds__(256) void scale_kernel(
        const float* __restrict__ x, const float* __restrict__ g,
        float* __restrict__ out) {
    const int base = blockIdx.x * 1024 + threadIdx.x;
    #pragma unroll
    for (int i = 0; i < 4; ++i) {
        const int chunk = base + i * 256;
        const int bc = chunk / CHUNKS_PER_PLANE;   // magic-multiply
        const float gv = g[bc];
        float4 v = ((const float4*)x)[chunk];
        v.x *= gv; v.y *= gv; v.z *= gv; v.w *= gv;
        ((float4*)out)[chunk] = v;
    }
}

extern "C" void kernel_launch(void* const* d_in, const int* in_sizes, int n_in,
                              void* d_out, int out_size, void* d_ws, size_t ws_size,
                              hipStream_t stream) {
    const float* x  = (const float*)d_in[0];
    const float* w1 = (const float*)d_in[1];
    const float* b1 = (const float*)d_in[2];
    const float* w2 = (const float*)d_in[3];
    const float* b2 = (const float*)d_in[4];
    float* out = (float*)d_out;

    float* s = (float*)d_ws;              // 8192 floats
    float* g = s + BATCH * CH;            // 8192 floats

    pool_kernel <<<BATCH * CH / 4, 256, 0, stream>>>(x, s);
    mlp_kernel  <<<BATCH, 256, 0, stream>>>(s, w1, b1, w2, b2, g);
    scale_kernel<<<SCALE_BLOCKS, 256, 0, stream>>>(x, g, out);
}